// Round 3
// baseline (738.904 us; speedup 1.0000x reference)
//
#include <hip/hip_runtime.h>
#include <hip/hip_bf16.h>
#include <math.h>
#include <stdint.h>

#define TOK 4096
#define SEQ 2048
#define NDIM 2048
#define NH 16
#define QR 1536
#define KVR 512
#define NOPE_D 128
#define QKH 192
#define QDIM 3072
#define KVDIM 4096
#define CW 640
#define ODIM 2048

typedef __attribute__((ext_vector_type(4))) float f32x4;
typedef __attribute__((ext_vector_type(8))) __bf16 bf16x8;
typedef __attribute__((ext_vector_type(8))) unsigned short u16x8;
typedef __attribute__((ext_vector_type(4))) unsigned short u16x4;

__device__ inline unsigned short f2bf(float f) {
  union { float f; uint32_t u; } v; v.f = f;
  uint32_t r = (v.u + 0x7FFFu + ((v.u >> 16) & 1u)) >> 16;
  return (unsigned short)r;
}
__device__ inline float bf2f(unsigned short s) {
  union { uint32_t u; float f; } v; v.u = ((uint32_t)s) << 16;
  return v.f;
}

// async global->LDS, 16B per lane. LDS dest is wave-uniform base + lane*16.
__device__ inline void gload16(const void* g, void* l) {
  __builtin_amdgcn_global_load_lds(
      (const __attribute__((address_space(1))) unsigned int*)g,
      (__attribute__((address_space(3))) unsigned int*)l, 16, 0, 0);
}

__global__ __launch_bounds__(256) void cvt_kernel(const float* __restrict__ in,
                                                  unsigned short* __restrict__ out, long n) {
  long i = ((long)blockIdx.x * 256 + threadIdx.x) * 4;
  if (i >= n) return;
  f32x4 v = *(const f32x4*)(in + i);
  u16x4 o;
  #pragma unroll
  for (int j = 0; j < 4; j++) o[j] = f2bf(v[j]);
  *(u16x4*)(out + i) = o;
}

__global__ __launch_bounds__(256) void zero_kernel(unsigned short* __restrict__ out, long n) {
  long i = ((long)blockIdx.x * 256 + threadIdx.x) * 4;
  if (i >= n) return;
  u16x4 z = {0, 0, 0, 0};
  *(u16x4*)(out + i) = z;
}

__device__ inline void storev(unsigned short* p, float v) { *p = f2bf(v); }
__device__ inline void storev(float* p, float v) { *p = v; }

// C[M,N] = A[M,K] (row-major, lda) * B[N,K]^T (row-major, ldb)
// grid: (N/128, M/128), block 256 (4 waves, 2x2 of 64x64). m97 structure:
// global_load_lds width=16 staging, linear [128][32] LDS, 2 barriers/K-step.
template <typename OutT>
__global__ __launch_bounds__(256) void gemm_bt(
    const unsigned short* __restrict__ A, int lda,
    const unsigned short* __restrict__ B, int ldb,
    OutT* __restrict__ C, int ldc, int K) {
  __shared__ unsigned short lA[128 * 32];
  __shared__ unsigned short lB[128 * 32];
  const int tid = threadIdx.x;
  const int lane = tid & 63, wave = tid >> 6;
  const int wr = wave >> 1, wc = wave & 1;
  const int l16 = lane & 15, lhi = lane >> 4;
  const long bm = (long)blockIdx.y * 128, bn = (long)blockIdx.x * 128;
  f32x4 acc[4][4];
  #pragma unroll
  for (int m = 0; m < 4; m++)
    #pragma unroll
    for (int n = 0; n < 4; n++) acc[m][n] = (f32x4){0.f, 0.f, 0.f, 0.f};
  // staging: wave w covers 16 rows per call; lane -> (row = w*16 + lane/4, col = (lane&3)*8)
  const int srow = wave * 16 + (lane >> 2);
  const int scol = (lane & 3) * 8;
  const unsigned short* Ag0 = A + (bm + srow) * lda + scol;
  const unsigned short* Ag1 = A + (bm + 64 + srow) * lda + scol;
  const unsigned short* Bg0 = B + (bn + srow) * ldb + scol;
  const unsigned short* Bg1 = B + (bn + 64 + srow) * ldb + scol;
  unsigned short* lA0 = &lA[wave * 512];
  unsigned short* lA1 = &lA[2048 + wave * 512];
  unsigned short* lB0 = &lB[wave * 512];
  unsigned short* lB1 = &lB[2048 + wave * 512];
  for (int k0 = 0; k0 < K; k0 += 32) {
    __syncthreads();
    gload16(Ag0 + k0, lA0);
    gload16(Ag1 + k0, lA1);
    gload16(Bg0 + k0, lB0);
    gload16(Bg1 + k0, lB1);
    __syncthreads();
    bf16x8 af[4], bfv[4];
    #pragma unroll
    for (int m = 0; m < 4; m++)
      af[m] = *(const bf16x8*)&lA[(wr * 64 + m * 16 + l16) * 32 + lhi * 8];
    #pragma unroll
    for (int n = 0; n < 4; n++)
      bfv[n] = *(const bf16x8*)&lB[(wc * 64 + n * 16 + l16) * 32 + lhi * 8];
    #pragma unroll
    for (int m = 0; m < 4; m++)
      #pragma unroll
      for (int n = 0; n < 4; n++)
        acc[m][n] = __builtin_amdgcn_mfma_f32_16x16x32_bf16(af[m], bfv[n], acc[m][n], 0, 0, 0);
  }
  #pragma unroll
  for (int m = 0; m < 4; m++)
    #pragma unroll
    for (int n = 0; n < 4; n++) {
      long row = bm + wr * 64 + m * 16 + lhi * 4;
      long col = bn + wc * 64 + n * 16 + l16;
      #pragma unroll
      for (int i = 0; i < 4; i++) storev(&C[(row + i) * ldc + col], acc[m][n][i]);
    }
}

// in-place rmsnorm of bf16 rows; one block per row
__global__ __launch_bounds__(256) void rmsnorm_kernel(unsigned short* __restrict__ buf,
                                                      const float* __restrict__ w,
                                                      int width, int lda) {
  const int tid = threadIdx.x;
  unsigned short* p = buf + (long)blockIdx.x * lda;
  float ss = 0.f;
  const int nc = width >> 2;
  for (int c = tid; c < nc; c += 256) {
    u16x4 v = *(const u16x4*)(p + c * 4);
    #pragma unroll
    for (int j = 0; j < 4; j++) { float f = bf2f(v[j]); ss += f * f; }
  }
  #pragma unroll
  for (int off = 32; off; off >>= 1) ss += __shfl_xor(ss, off);
  __shared__ float red[4];
  if ((tid & 63) == 0) red[tid >> 6] = ss;
  __syncthreads();
  float tot = red[0] + red[1] + red[2] + red[3];
  float rn = rsqrtf(tot / (float)width + 1e-6f);
  for (int c = tid; c < nc; c += 256) {
    u16x4 v = *(const u16x4*)(p + c * 4);
    u16x4 o;
    #pragma unroll
    for (int j = 0; j < 4; j++) o[j] = f2bf(bf2f(v[j]) * rn * w[c * 4 + j]);
    *(u16x4*)(p + c * 4) = o;
  }
}

__global__ __launch_bounds__(256) void rope_q_kernel(unsigned short* __restrict__ q,
                                                     const float* __restrict__ fr) {
  int idx = blockIdx.x * 256 + threadIdx.x;  // (tok, h, pair)
  int pair = idx & 31, h = (idx >> 5) & 15, tok = idx >> 9;
  int s = tok & (SEQ - 1);
  unsigned short* p = q + (long)tok * QDIM + h * QKH + NOPE_D + pair * 2;
  float c = fr[(s * 32 + pair) * 2 + 0], sn = fr[(s * 32 + pair) * 2 + 1];
  float xr = bf2f(p[0]), xi = bf2f(p[1]);
  p[0] = f2bf(xr * c - xi * sn);
  p[1] = f2bf(xr * sn + xi * c);
}

__global__ __launch_bounds__(256) void rope_k_kernel(unsigned short* __restrict__ cb,
                                                     const float* __restrict__ fr) {
  int idx = blockIdx.x * 256 + threadIdx.x;  // (tok, pair)
  int pair = idx & 31, tok = idx >> 5;
  int s = tok & (SEQ - 1);
  unsigned short* p = cb + (long)tok * CW + KVR + pair * 2;
  float c = fr[(s * 32 + pair) * 2 + 0], sn = fr[(s * 32 + pair) * 2 + 1];
  float xr = bf2f(p[0]), xi = bf2f(p[1]);
  p[0] = f2bf(xr * c - xi * sn);
  p[1] = f2bf(xr * sn + xi * c);
}

// Flash-style causal attention. grid (S/64, NH, B), block 256 (4 waves x 16 q-rows).
// T14 async-STAGE: prefetch next tile into regs during compute of current tile.
// qt reversed (longest blocks first) for causal load-balance.
__global__ __launch_bounds__(256) void attn_kernel(
    const unsigned short* __restrict__ qb,
    const unsigned short* __restrict__ kvb,
    const unsigned short* __restrict__ cb,
    unsigned short* __restrict__ ao) {
  const int qt = gridDim.x - 1 - blockIdx.x;
  const int h = blockIdx.y, b = blockIdx.z;
  const int tid = threadIdx.x, wave = tid >> 6, lane = tid & 63;
  const int l16 = lane & 15, lhi = lane >> 4;
  const long tbase = (long)b * SEQ;
  const int q0 = qt * 64;
  __shared__ unsigned short lK[64][200];   // [key][d 0..191]
  __shared__ unsigned short lV[128][72];   // [d][key]  (transposed)
  __shared__ unsigned short lP[4][16][72]; // per-wave P tile
  const float scale = 0.0721687836f;  // 1/sqrt(192)
  bf16x8 qf[6];
  {
    const unsigned short* qg = qb + (tbase + q0 + wave * 16 + l16) * QDIM + h * QKH;
    #pragma unroll
    for (int d = 0; d < 6; d++) qf[d] = *(const bf16x8*)(qg + d * 32 + lhi * 8);
  }
  f32x4 oacc[8];
  #pragma unroll
  for (int n = 0; n < 8; n++) oacc[n] = (f32x4){0.f, 0.f, 0.f, 0.f};
  float mr[4], lr[4];
  #pragma unroll
  for (int i = 0; i < 4; i++) { mr[i] = -1e30f; lr[i] = 0.f; }

  // prefetch registers
  u16x8 kreg[6];
  u16x8 vreg[4];
  const int vpr = tid & 31, vd0 = (tid >> 5) * 16;

  auto load_tile = [&](int kt) {
    const int k0 = kt * 64;
    #pragma unroll
    for (int it = 0; it < 6; it++) {
      int c = tid + it * 256;
      int row = c / 24, ch = c % 24;
      const unsigned short* src = (ch < 16)
          ? kvb + (tbase + k0 + row) * KVDIM + h * 256 + ch * 8
          : cb + (tbase + k0 + row) * CW + KVR + (ch - 16) * 8;
      kreg[it] = *(const u16x8*)src;
    }
    const unsigned short* v0 = kvb + (tbase + k0 + 2 * vpr) * KVDIM + h * 256 + 128 + vd0;
    vreg[0] = *(const u16x8*)v0;
    vreg[1] = *(const u16x8*)(v0 + 8);
    vreg[2] = *(const u16x8*)(v0 + KVDIM);
    vreg[3] = *(const u16x8*)(v0 + KVDIM + 8);
  };
  auto write_tile = [&]() {
    #pragma unroll
    for (int it = 0; it < 6; it++) {
      int c = tid + it * 256;
      int row = c / 24, ch = c % 24;
      *(u16x8*)&lK[row][ch * 8] = kreg[it];
    }
    #pragma unroll
    for (int j = 0; j < 8; j++) {
      *(uint32_t*)&lV[vd0 + j][2 * vpr] = (uint32_t)vreg[0][j] | ((uint32_t)vreg[2][j] << 16);
      *(uint32_t*)&lV[vd0 + 8 + j][2 * vpr] = (uint32_t)vreg[1][j] | ((uint32_t)vreg[3][j] << 16);
    }
  };

  const int nkt = qt + 1;
  load_tile(0);
  for (int kt = 0; kt < nkt; kt++) {
    const int k0 = kt * 64;
    __syncthreads();          // all waves done reading previous tile's LDS
    write_tile();
    __syncthreads();          // staged tile visible
    if (kt + 1 < nkt) load_tile(kt + 1);  // flies during compute below
    // QK^T: wave's 16 q-rows x 64 keys
    f32x4 sc[4];
    #pragma unroll
    for (int ks = 0; ks < 4; ks++) {
      sc[ks] = (f32x4){0.f, 0.f, 0.f, 0.f};
      #pragma unroll
      for (int d = 0; d < 6; d++) {
        bf16x8 kf = *(const bf16x8*)&lK[ks * 16 + l16][d * 32 + lhi * 8];
        sc[ks] = __builtin_amdgcn_mfma_f32_16x16x32_bf16(qf[d], kf, sc[ks], 0, 0, 0);
      }
    }
    float sv[4][4];
    const bool diag = (kt == qt);
    #pragma unroll
    for (int ks = 0; ks < 4; ks++)
      #pragma unroll
      for (int i = 0; i < 4; i++) {
        float v = sc[ks][i] * scale;
        if (diag && (k0 + ks * 16 + l16) > (q0 + wave * 16 + lhi * 4 + i)) v = -1e30f;
        sv[ks][i] = v;
      }
    float fac[4];
    #pragma unroll
    for (int i = 0; i < 4; i++) {
      float mx = fmaxf(fmaxf(sv[0][i], sv[1][i]), fmaxf(sv[2][i], sv[3][i]));
      #pragma unroll
      for (int off = 1; off < 16; off <<= 1) mx = fmaxf(mx, __shfl_xor(mx, off));
      float mn = fmaxf(mr[i], mx);
      fac[i] = exp2f((mr[i] - mn) * 1.44269504f);
      mr[i] = mn;
    }
    float rs[4] = {0.f, 0.f, 0.f, 0.f};
    unsigned short pb[4][4];
    #pragma unroll
    for (int ks = 0; ks < 4; ks++)
      #pragma unroll
      for (int i = 0; i < 4; i++) {
        float pv = exp2f((sv[ks][i] - mr[i]) * 1.44269504f);
        rs[i] += pv;
        pb[ks][i] = f2bf(pv);
      }
    #pragma unroll
    for (int i = 0; i < 4; i++) {
      float r = rs[i];
      #pragma unroll
      for (int off = 1; off < 16; off <<= 1) r += __shfl_xor(r, off);
      lr[i] = lr[i] * fac[i] + r;
    }
    #pragma unroll
    for (int n = 0; n < 8; n++) {
      f32x4 t = oacc[n];
      t[0] *= fac[0]; t[1] *= fac[1]; t[2] *= fac[2]; t[3] *= fac[3];
      oacc[n] = t;
    }
    // write P (per-wave region, intra-wave dependency only)
    #pragma unroll
    for (int ks = 0; ks < 4; ks++)
      #pragma unroll
      for (int i = 0; i < 4; i++)
        lP[wave][lhi * 4 + i][ks * 16 + l16] = pb[ks][i];
    // PV: O += P(16x64) * V(64x128)
    #pragma unroll
    for (int kk = 0; kk < 2; kk++) {
      bf16x8 pf = *(const bf16x8*)&lP[wave][l16][kk * 32 + lhi * 8];
      #pragma unroll
      for (int n = 0; n < 8; n++) {
        bf16x8 vf = *(const bf16x8*)&lV[n * 16 + l16][kk * 32 + lhi * 8];
        oacc[n] = __builtin_amdgcn_mfma_f32_16x16x32_bf16(pf, vf, oacc[n], 0, 0, 0);
      }
    }
  }
  #pragma unroll
  for (int n = 0; n < 8; n++)
    #pragma unroll
    for (int i = 0; i < 4; i++) {
      long row = tbase + q0 + wave * 16 + lhi * 4 + i;
      ao[row * ODIM + h * 128 + n * 16 + l16] = f2bf(oacc[n][i] / lr[i]);
    }
}

extern "C" void kernel_launch(void* const* d_in, const int* in_sizes, int n_in,
                              void* d_out, int out_size, void* d_ws, size_t ws_size,
                              hipStream_t stream) {
  const float* x = (const float*)d_in[0];
  const float* fr = (const float*)d_in[1];
  const float* wq_a = (const float*)d_in[2];
  const float* qnw = (const float*)d_in[3];
  const float* wq_b = (const float*)d_in[4];
  const float* wkv_a = (const float*)d_in[5];
  const float* kvnw = (const float*)d_in[6];
  const float* wkv_b = (const float*)d_in[7];
  const float* wo = (const float*)d_in[8];
  float* out = (float*)d_out;

  char* ws = (char*)d_ws;
  size_t o = 0;
  unsigned short* xb = (unsigned short*)(ws + o);    o += (size_t)TOK * NDIM * 2;
  unsigned short* wqab = (unsigned short*)(ws + o);  o += (size_t)QR * NDIM * 2;
  unsigned short* wqbb = (unsigned short*)(ws + o);  o += (size_t)QDIM * QR * 2;
  unsigned short* wkvab = (unsigned short*)(ws + o); o += (size_t)CW * NDIM * 2;
  unsigned short* wkvbb = (unsigned short*)(ws + o); o += (size_t)KVDIM * KVR * 2;
  unsigned short* wob = (unsigned short*)(ws + o);   o += (size_t)NDIM * ODIM * 2;
  unsigned short* cq = (unsigned short*)(ws + o);    o += (size_t)TOK * QR * 2;
  unsigned short* qbuf = (unsigned short*)(ws + o);  o += (size_t)TOK * QDIM * 2;
  unsigned short* cbuf = (unsigned short*)(ws + o);  o += (size_t)TOK * CW * 2;
  unsigned short* kvbuf = (unsigned short*)(ws + o); o += (size_t)TOK * KVDIM * 2;
  unsigned short* aout = (unsigned short*)(ws + o);  o += (size_t)TOK * ODIM * 2;

  cvt_kernel<<<(TOK * (long)NDIM) / 1024, 256, 0, stream>>>(x, xb, (long)TOK * NDIM);
  cvt_kernel<<<((long)QR * NDIM) / 1024, 256, 0, stream>>>(wq_a, wqab, (long)QR * NDIM);
  cvt_kernel<<<((long)QDIM * QR) / 1024, 256, 0, stream>>>(wq_b, wqbb, (long)QDIM * QR);
  cvt_kernel<<<((long)576 * NDIM) / 1024, 256, 0, stream>>>(wkv_a, wkvab, (long)576 * NDIM);
  zero_kernel<<<((long)64 * NDIM) / 1024, 256, 0, stream>>>(wkvab + (size_t)576 * NDIM,
                                                            (long)64 * NDIM);
  cvt_kernel<<<((long)KVDIM * KVR) / 1024, 256, 0, stream>>>(wkv_b, wkvbb, (long)KVDIM * KVR);
  cvt_kernel<<<((long)NDIM * ODIM) / 1024, 256, 0, stream>>>(wo, wob, (long)NDIM * ODIM);

  dim3 blk(256);
  gemm_bt<unsigned short><<<dim3(QR / 128, TOK / 128), blk, 0, stream>>>(
      xb, NDIM, wqab, NDIM, cq, QR, NDIM);
  gemm_bt<unsigned short><<<dim3(CW / 128, TOK / 128), blk, 0, stream>>>(
      xb, NDIM, wkvab, NDIM, cbuf, CW, NDIM);
  rmsnorm_kernel<<<TOK, 256, 0, stream>>>(cq, qnw, QR, QR);
  rmsnorm_kernel<<<TOK, 256, 0, stream>>>(cbuf, kvnw, KVR, CW);
  gemm_bt<unsigned short><<<dim3(QDIM / 128, TOK / 128), blk, 0, stream>>>(
      cq, QR, wqbb, QR, qbuf, QDIM, QR);
  gemm_bt<unsigned short><<<dim3(KVDIM / 128, TOK / 128), blk, 0, stream>>>(
      cbuf, CW, wkvbb, KVR, kvbuf, KVDIM, KVR);
  rope_q_kernel<<<(TOK * NH * 32) / 256, 256, 0, stream>>>(qbuf, fr);
  rope_k_kernel<<<(TOK * 32) / 256, 256, 0, stream>>>(cbuf, fr);
  attn_kernel<<<dim3(SEQ / 64, NH, 2), blk, 0, stream>>>(qbuf, kvbuf, cbuf, aout);
  gemm_bt<float><<<dim3(ODIM / 128, TOK / 128), blk, 0, stream>>>(
      aout, ODIM, wob, ODIM, out, ODIM, ODIM);
}

// Round 4
// 611.221 us; speedup vs baseline: 1.2089x; 1.2089x over previous
//
#include <hip/hip_runtime.h>
#include <hip/hip_bf16.h>
#include <math.h>
#include <stdint.h>

#define TOK 4096
#define SEQ 2048
#define NDIM 2048
#define NH 16
#define QR 1536
#define KVR 512
#define NOPE_D 128
#define QKH 192
#define QDIM 3072
#define KVDIM 4096
#define CW 640
#define ODIM 2048

typedef __attribute__((ext_vector_type(4))) float f32x4;
typedef __attribute__((ext_vector_type(8))) __bf16 bf16x8;
typedef __attribute__((ext_vector_type(8))) unsigned short u16x8;
typedef __attribute__((ext_vector_type(4))) unsigned short u16x4;

__device__ inline unsigned short f2bf(float f) {
  union { float f; uint32_t u; } v; v.f = f;
  uint32_t r = (v.u + 0x7FFFu + ((v.u >> 16) & 1u)) >> 16;
  return (unsigned short)r;
}
__device__ inline float bf2f(unsigned short s) {
  union { uint32_t u; float f; } v; v.u = ((uint32_t)s) << 16;
  return v.f;
}

// async global->LDS, 16B per lane. LDS dest is wave-uniform base + lane*16.
__device__ inline void gload16(const void* g, void* l) {
  __builtin_amdgcn_global_load_lds(
      (const __attribute__((address_space(1))) unsigned int*)g,
      (__attribute__((address_space(3))) unsigned int*)l, 16, 0, 0);
}

__global__ __launch_bounds__(256) void cvt_kernel(const float* __restrict__ in,
                                                  unsigned short* __restrict__ out, long n) {
  long i = ((long)blockIdx.x * 256 + threadIdx.x) * 4;
  if (i >= n) return;
  f32x4 v = *(const f32x4*)(in + i);
  u16x4 o;
  #pragma unroll
  for (int j = 0; j < 4; j++) o[j] = f2bf(v[j]);
  *(u16x4*)(out + i) = o;
}

__global__ __launch_bounds__(256) void zero_kernel(unsigned short* __restrict__ out, long n) {
  long i = ((long)blockIdx.x * 256 + threadIdx.x) * 4;
  if (i >= n) return;
  u16x4 z = {0, 0, 0, 0};
  *(u16x4*)(out + i) = z;
}

__device__ inline void storev(unsigned short* p, float v) { *p = f2bf(v); }
__device__ inline void storev(float* p, float v) { *p = v; }

// C[M,N] = A[M,K] (row-major, lda) * B[N,K]^T (row-major, ldb)
// grid: (N/128, M/128), block 256 (4 waves, 2x2 of 64x64). m97 structure:
// global_load_lds width=16 staging, linear [128][32] LDS, 2 barriers/K-step.
template <typename OutT>
__global__ __launch_bounds__(256) void gemm_bt(
    const unsigned short* __restrict__ A, int lda,
    const unsigned short* __restrict__ B, int ldb,
    OutT* __restrict__ C, int ldc, int K) {
  __shared__ unsigned short lA[128 * 32];
  __shared__ unsigned short lB[128 * 32];
  const int tid = threadIdx.x;
  const int lane = tid & 63, wave = tid >> 6;
  const int wr = wave >> 1, wc = wave & 1;
  const int l16 = lane & 15, lhi = lane >> 4;
  const long bm = (long)blockIdx.y * 128, bn = (long)blockIdx.x * 128;
  f32x4 acc[4][4];
  #pragma unroll
  for (int m = 0; m < 4; m++)
    #pragma unroll
    for (int n = 0; n < 4; n++) acc[m][n] = (f32x4){0.f, 0.f, 0.f, 0.f};
  // staging: wave w covers 16 rows per call; lane -> (row = w*16 + lane/4, col = (lane&3)*8)
  const int srow = wave * 16 + (lane >> 2);
  const int scol = (lane & 3) * 8;
  const unsigned short* Ag0 = A + (bm + srow) * lda + scol;
  const unsigned short* Ag1 = A + (bm + 64 + srow) * lda + scol;
  const unsigned short* Bg0 = B + (bn + srow) * ldb + scol;
  const unsigned short* Bg1 = B + (bn + 64 + srow) * ldb + scol;
  unsigned short* lA0 = &lA[wave * 512];
  unsigned short* lA1 = &lA[2048 + wave * 512];
  unsigned short* lB0 = &lB[wave * 512];
  unsigned short* lB1 = &lB[2048 + wave * 512];
  for (int k0 = 0; k0 < K; k0 += 32) {
    __syncthreads();
    gload16(Ag0 + k0, lA0);
    gload16(Ag1 + k0, lA1);
    gload16(Bg0 + k0, lB0);
    gload16(Bg1 + k0, lB1);
    __syncthreads();
    bf16x8 af[4], bfv[4];
    #pragma unroll
    for (int m = 0; m < 4; m++)
      af[m] = *(const bf16x8*)&lA[(wr * 64 + m * 16 + l16) * 32 + lhi * 8];
    #pragma unroll
    for (int n = 0; n < 4; n++)
      bfv[n] = *(const bf16x8*)&lB[(wc * 64 + n * 16 + l16) * 32 + lhi * 8];
    #pragma unroll
    for (int m = 0; m < 4; m++)
      #pragma unroll
      for (int n = 0; n < 4; n++)
        acc[m][n] = __builtin_amdgcn_mfma_f32_16x16x32_bf16(af[m], bfv[n], acc[m][n], 0, 0, 0);
  }
  #pragma unroll
  for (int m = 0; m < 4; m++)
    #pragma unroll
    for (int n = 0; n < 4; n++) {
      long row = bm + wr * 64 + m * 16 + lhi * 4;
      long col = bn + wc * 64 + n * 16 + l16;
      #pragma unroll
      for (int i = 0; i < 4; i++) storev(&C[(row + i) * ldc + col], acc[m][n][i]);
    }
}

// in-place rmsnorm of bf16 rows; one block per row
__global__ __launch_bounds__(256) void rmsnorm_kernel(unsigned short* __restrict__ buf,
                                                      const float* __restrict__ w,
                                                      int width, int lda) {
  const int tid = threadIdx.x;
  unsigned short* p = buf + (long)blockIdx.x * lda;
  float ss = 0.f;
  const int nc = width >> 2;
  for (int c = tid; c < nc; c += 256) {
    u16x4 v = *(const u16x4*)(p + c * 4);
    #pragma unroll
    for (int j = 0; j < 4; j++) { float f = bf2f(v[j]); ss += f * f; }
  }
  #pragma unroll
  for (int off = 32; off; off >>= 1) ss += __shfl_xor(ss, off);
  __shared__ float red[4];
  if ((tid & 63) == 0) red[tid >> 6] = ss;
  __syncthreads();
  float tot = red[0] + red[1] + red[2] + red[3];
  float rn = rsqrtf(tot / (float)width + 1e-6f);
  for (int c = tid; c < nc; c += 256) {
    u16x4 v = *(const u16x4*)(p + c * 4);
    u16x4 o;
    #pragma unroll
    for (int j = 0; j < 4; j++) o[j] = f2bf(bf2f(v[j]) * rn * w[c * 4 + j]);
    *(u16x4*)(p + c * 4) = o;
  }
}

__global__ __launch_bounds__(256) void rope_q_kernel(unsigned short* __restrict__ q,
                                                     const float* __restrict__ fr) {
  int idx = blockIdx.x * 256 + threadIdx.x;  // (tok, h, pair)
  int pair = idx & 31, h = (idx >> 5) & 15, tok = idx >> 9;
  int s = tok & (SEQ - 1);
  unsigned short* p = q + (long)tok * QDIM + h * QKH + NOPE_D + pair * 2;
  float c = fr[(s * 32 + pair) * 2 + 0], sn = fr[(s * 32 + pair) * 2 + 1];
  float xr = bf2f(p[0]), xi = bf2f(p[1]);
  p[0] = f2bf(xr * c - xi * sn);
  p[1] = f2bf(xr * sn + xi * c);
}

__global__ __launch_bounds__(256) void rope_k_kernel(unsigned short* __restrict__ cb,
                                                     const float* __restrict__ fr) {
  int idx = blockIdx.x * 256 + threadIdx.x;  // (tok, pair)
  int pair = idx & 31, tok = idx >> 5;
  int s = tok & (SEQ - 1);
  unsigned short* p = cb + (long)tok * CW + KVR + pair * 2;
  float c = fr[(s * 32 + pair) * 2 + 0], sn = fr[(s * 32 + pair) * 2 + 1];
  float xr = bf2f(p[0]), xi = bf2f(p[1]);
  p[0] = f2bf(xr * c - xi * sn);
  p[1] = f2bf(xr * sn + xi * c);
}

// Flash-style causal attention. grid (S/128, NH, B), block 512 (8 waves x 16 q-rows).
// QBLK=128: each KV-tile stage serves 128 q-rows (2x reuse vs QBLK=64).
// 512 blocks = 2/CU, all co-resident -> no dispatch tail.
__global__ __launch_bounds__(512, 4) void attn_kernel(
    const unsigned short* __restrict__ qb,
    const unsigned short* __restrict__ kvb,
    const unsigned short* __restrict__ cb,
    unsigned short* __restrict__ ao) {
  const int qt = blockIdx.x, h = blockIdx.y, b = blockIdx.z;
  const int tid = threadIdx.x, wave = tid >> 6, lane = tid & 63;
  const int l16 = lane & 15, lhi = lane >> 4;
  const long tbase = (long)b * SEQ;
  const int q0 = qt * 128;
  __shared__ unsigned short lK[64][200];   // [key][d 0..191]
  __shared__ unsigned short lV[128][72];   // [d][key]  (transposed)
  __shared__ unsigned short lP[8][16][72]; // per-wave P tile
  const float scale = 0.0721687836f;  // 1/sqrt(192)
  bf16x8 qf[6];
  {
    const unsigned short* qg = qb + (tbase + q0 + wave * 16 + l16) * QDIM + h * QKH;
    #pragma unroll
    for (int d = 0; d < 6; d++) qf[d] = *(const bf16x8*)(qg + d * 32 + lhi * 8);
  }
  f32x4 oacc[8];
  #pragma unroll
  for (int n = 0; n < 8; n++) oacc[n] = (f32x4){0.f, 0.f, 0.f, 0.f};
  float mr[4], lr[4];
  #pragma unroll
  for (int i = 0; i < 4; i++) { mr[i] = -1e30f; lr[i] = 0.f; }

  const int vpr = tid & 31, vd0 = (tid >> 5) * 8;
  const int nkt = 2 * qt + 2;
  for (int kt = 0; kt < nkt; kt++) {
    const int k0 = kt * 64;
    __syncthreads();
    // stage K tile: 64 rows x 192 (128 nope from kv, 64 rope from c); 3 chunks/thread
    #pragma unroll
    for (int it = 0; it < 3; it++) {
      int c = tid + it * 512;
      int row = c / 24, ch = c % 24;
      const unsigned short* src = (ch < 16)
          ? kvb + (tbase + k0 + row) * KVDIM + h * 256 + ch * 8
          : cb + (tbase + k0 + row) * CW + KVR + (ch - 16) * 8;
      *(u16x8*)&lK[row][ch * 8] = *(const u16x8*)src;
    }
    // stage V transposed: thread handles keys {2p,2p+1} x 8 d
    {
      const unsigned short* v0 = kvb + (tbase + k0 + 2 * vpr) * KVDIM + h * 256 + 128 + vd0;
      u16x8 x0 = *(const u16x8*)v0;
      u16x8 y0 = *(const u16x8*)(v0 + KVDIM);
      #pragma unroll
      for (int j = 0; j < 8; j++)
        *(uint32_t*)&lV[vd0 + j][2 * vpr] = (uint32_t)x0[j] | ((uint32_t)y0[j] << 16);
    }
    __syncthreads();
    // QK^T: wave's 16 q-rows x 64 keys
    f32x4 sc[4];
    #pragma unroll
    for (int ks = 0; ks < 4; ks++) {
      sc[ks] = (f32x4){0.f, 0.f, 0.f, 0.f};
      #pragma unroll
      for (int d = 0; d < 6; d++) {
        bf16x8 kf = *(const bf16x8*)&lK[ks * 16 + l16][d * 32 + lhi * 8];
        sc[ks] = __builtin_amdgcn_mfma_f32_16x16x32_bf16(qf[d], kf, sc[ks], 0, 0, 0);
      }
    }
    // scale + causal mask (in-place; diagonal spans tiles at QBLK=128)
    #pragma unroll
    for (int ks = 0; ks < 4; ks++)
      #pragma unroll
      for (int i = 0; i < 4; i++) {
        float v = sc[ks][i] * scale;
        if ((k0 + ks * 16 + l16) > (q0 + wave * 16 + lhi * 4 + i)) v = -1e30f;
        sc[ks][i] = v;
      }
    float fac[4];
    #pragma unroll
    for (int i = 0; i < 4; i++) {
      float mx = fmaxf(fmaxf(sc[0][i], sc[1][i]), fmaxf(sc[2][i], sc[3][i]));
      #pragma unroll
      for (int off = 1; off < 16; off <<= 1) mx = fmaxf(mx, __shfl_xor(mx, off));
      float mn = fmaxf(mr[i], mx);
      fac[i] = exp2f((mr[i] - mn) * 1.44269504f);
      mr[i] = mn;
    }
    float rs[4] = {0.f, 0.f, 0.f, 0.f};
    #pragma unroll
    for (int ks = 0; ks < 4; ks++)
      #pragma unroll
      for (int i = 0; i < 4; i++) {
        float pv = exp2f((sc[ks][i] - mr[i]) * 1.44269504f);
        rs[i] += pv;
        lP[wave][lhi * 4 + i][ks * 16 + l16] = f2bf(pv);
      }
    #pragma unroll
    for (int i = 0; i < 4; i++) {
      float r = rs[i];
      #pragma unroll
      for (int off = 1; off < 16; off <<= 1) r += __shfl_xor(r, off);
      lr[i] = lr[i] * fac[i] + r;
    }
    #pragma unroll
    for (int n = 0; n < 8; n++) {
      f32x4 t = oacc[n];
      t[0] *= fac[0]; t[1] *= fac[1]; t[2] *= fac[2]; t[3] *= fac[3];
      oacc[n] = t;
    }
    // PV: O += P(16x64) * V(64x128)
    #pragma unroll
    for (int kk = 0; kk < 2; kk++) {
      bf16x8 pf = *(const bf16x8*)&lP[wave][l16][kk * 32 + lhi * 8];
      #pragma unroll
      for (int n = 0; n < 8; n++) {
        bf16x8 vf = *(const bf16x8*)&lV[n * 16 + l16][kk * 32 + lhi * 8];
        oacc[n] = __builtin_amdgcn_mfma_f32_16x16x32_bf16(pf, vf, oacc[n], 0, 0, 0);
      }
    }
  }
  #pragma unroll
  for (int n = 0; n < 8; n++)
    #pragma unroll
    for (int i = 0; i < 4; i++) {
      long row = tbase + q0 + wave * 16 + lhi * 4 + i;
      ao[row * ODIM + h * 128 + n * 16 + l16] = f2bf(oacc[n][i] / lr[i]);
    }
}

extern "C" void kernel_launch(void* const* d_in, const int* in_sizes, int n_in,
                              void* d_out, int out_size, void* d_ws, size_t ws_size,
                              hipStream_t stream) {
  const float* x = (const float*)d_in[0];
  const float* fr = (const float*)d_in[1];
  const float* wq_a = (const float*)d_in[2];
  const float* qnw = (const float*)d_in[3];
  const float* wq_b = (const float*)d_in[4];
  const float* wkv_a = (const float*)d_in[5];
  const float* kvnw = (const float*)d_in[6];
  const float* wkv_b = (const float*)d_in[7];
  const float* wo = (const float*)d_in[8];
  float* out = (float*)d_out;

  char* ws = (char*)d_ws;
  size_t o = 0;
  unsigned short* xb = (unsigned short*)(ws + o);    o += (size_t)TOK * NDIM * 2;
  unsigned short* wqab = (unsigned short*)(ws + o);  o += (size_t)QR * NDIM * 2;
  unsigned short* wqbb = (unsigned short*)(ws + o);  o += (size_t)QDIM * QR * 2;
  unsigned short* wkvab = (unsigned short*)(ws + o); o += (size_t)CW * NDIM * 2;
  unsigned short* wkvbb = (unsigned short*)(ws + o); o += (size_t)KVDIM * KVR * 2;
  unsigned short* wob = (unsigned short*)(ws + o);   o += (size_t)NDIM * ODIM * 2;
  unsigned short* cq = (unsigned short*)(ws + o);    o += (size_t)TOK * QR * 2;
  unsigned short* qbuf = (unsigned short*)(ws + o);  o += (size_t)TOK * QDIM * 2;
  unsigned short* cbuf = (unsigned short*)(ws + o);  o += (size_t)TOK * CW * 2;
  unsigned short* kvbuf = (unsigned short*)(ws + o); o += (size_t)TOK * KVDIM * 2;
  unsigned short* aout = (unsigned short*)(ws + o);  o += (size_t)TOK * ODIM * 2;

  cvt_kernel<<<(TOK * (long)NDIM) / 1024, 256, 0, stream>>>(x, xb, (long)TOK * NDIM);
  cvt_kernel<<<((long)QR * NDIM) / 1024, 256, 0, stream>>>(wq_a, wqab, (long)QR * NDIM);
  cvt_kernel<<<((long)QDIM * QR) / 1024, 256, 0, stream>>>(wq_b, wqbb, (long)QDIM * QR);
  cvt_kernel<<<((long)576 * NDIM) / 1024, 256, 0, stream>>>(wkv_a, wkvab, (long)576 * NDIM);
  zero_kernel<<<((long)64 * NDIM) / 1024, 256, 0, stream>>>(wkvab + (size_t)576 * NDIM,
                                                            (long)64 * NDIM);
  cvt_kernel<<<((long)KVDIM * KVR) / 1024, 256, 0, stream>>>(wkv_b, wkvbb, (long)KVDIM * KVR);
  cvt_kernel<<<((long)NDIM * ODIM) / 1024, 256, 0, stream>>>(wo, wob, (long)NDIM * ODIM);

  dim3 blk(256);
  gemm_bt<unsigned short><<<dim3(QR / 128, TOK / 128), blk, 0, stream>>>(
      xb, NDIM, wqab, NDIM, cq, QR, NDIM);
  gemm_bt<unsigned short><<<dim3(CW / 128, TOK / 128), blk, 0, stream>>>(
      xb, NDIM, wkvab, NDIM, cbuf, CW, NDIM);
  rmsnorm_kernel<<<TOK, 256, 0, stream>>>(cq, qnw, QR, QR);
  rmsnorm_kernel<<<TOK, 256, 0, stream>>>(cbuf, kvnw, KVR, CW);
  gemm_bt<unsigned short><<<dim3(QDIM / 128, TOK / 128), blk, 0, stream>>>(
      cq, QR, wqbb, QR, qbuf, QDIM, QR);
  gemm_bt<unsigned short><<<dim3(KVDIM / 128, TOK / 128), blk, 0, stream>>>(
      cbuf, CW, wkvbb, KVR, kvbuf, KVDIM, KVR);
  rope_q_kernel<<<(TOK * NH * 32) / 256, 256, 0, stream>>>(qbuf, fr);
  rope_k_kernel<<<(TOK * 32) / 256, 256, 0, stream>>>(cbuf, fr);
  attn_kernel<<<dim3(SEQ / 128, NH, 2), 512, 0, stream>>>(qbuf, kvbuf, cbuf, aout);
  gemm_bt<float><<<dim3(ODIM / 128, TOK / 128), blk, 0, stream>>>(
      aout, ODIM, wob, ODIM, out, ODIM, ODIM);
}